// Round 12
// baseline (92.652 us; speedup 1.0000x reference)
//
#include <hip/hip_runtime.h>
#include <hip/hip_bf16.h>
#include <math.h>

// Problem constants: B=16, C=128, M=H*W=1024.
#define NB 16
#define NC 128
#define NM 1024
#define ZS 132   // loss LDS row stride (16B-aligned, bank-shifted; 132%4==0)

typedef __attribute__((ext_vector_type(8))) short  short8v;   // 8 bf16 = 4 VGPR
typedef __attribute__((ext_vector_type(4))) float  floatx4;   // MFMA 16x16 acc
typedef __attribute__((ext_vector_type(16))) float floatx16;  // MFMA 32x32 acc

__device__ __forceinline__ short bf16rne(float v)
{
    unsigned xb = __float_as_uint(v);
    return (short)((xb + 0x7FFFu + ((xb >> 16) & 1u)) >> 16);
}

// Persistent device scratch (fully rewritten every call -> deterministic).
// g_FH: fragment-linear bf16 hi for the MFMA argmin. chunk = (b*32+row/32)*8
// + k/16 is a 1KB wave fragment; lane = ((k>>3)&1)*32 | (row&31), 8 k/lane.
// g_T: token-major fp32 (contiguous 512B rows) for the loss gather.
__device__ unsigned short g_FH[2][NB * NM * NC];
__device__ float    g_T[2][NB * NM * NC];
__device__ float    g_npart[2][2][NB * NM];   // per-position norm partials (c-halves)
__device__ float    g_rval[NB][8][NM];        // row-min partials over 8 col-splits
__device__ unsigned g_ridx[NB][8][NM];
__device__ float    g_cval[NB][8][NM];        // col-min partials over 8 row-tiles
__device__ unsigned g_cidx[NB][8][NM];
__device__ float    g_accum[3];               // R,S,Q totals (atomicAdd; zeroed by
__device__ unsigned g_done;                   //  transpose each call) + ticket

// ---------------------------------------------------------------------------
// Transpose E[b][c][p] (c-major) -> g_T fp32 token-major + g_FH bf16-hi
// fragment-linear + per-position norm partials. float4 global loads (1KB/wave
// instr); LDS tile [64][65] keeps column reads conflict-free. Block (0,0,0)
// also zeroes the accumulator/ticket (atomicExch -> coherent for loss atomics).
__global__ __launch_bounds__(256)
void transpose_kernel(const float* __restrict__ e1, const float* __restrict__ e2)
{
    __shared__ float tile[64][65];
    __shared__ float s_np[4][64];
    const int z   = blockIdx.z;
    const int b   = z >> 1;
    const int mat = z & 1;
    const float* src = mat ? e2 : e1;
    const int p0 = blockIdx.x * 64;
    const int c0 = blockIdx.y * 64;
    const int t  = threadIdx.x;
    const int tj = t & 63;
    const int ti = t >> 6;               // 0..3

    if (z == 0 && blockIdx.x == 0 && blockIdx.y == 0) {
        if (t < 3) atomicExch(&g_accum[t], 0.0f);
        if (t == 3) atomicExch(&g_done, 0u);
    }

    const float* sb = src + (size_t)b * NC * NM;
    // vectorized loads: task id -> (c = id>>4, q = id&15), 1KB per wave instr
    #pragma unroll
    for (int i = 0; i < 4; ++i) {
        int id = i * 256 + t;
        int c = id >> 4, q = id & 15;
        float4 v = *reinterpret_cast<const float4*>(sb + (size_t)(c0 + c) * NM + p0 + q * 4);
        tile[c][q * 4 + 0] = v.x;
        tile[c][q * 4 + 1] = v.y;
        tile[c][q * 4 + 2] = v.z;
        tile[c][q * 4 + 3] = v.w;
    }
    __syncthreads();

    // fp32 token-major rows (contiguous in c, coalesced)
    float* db = g_T[mat] + (size_t)b * NM * NC;
    #pragma unroll
    for (int i = 0; i < 16; ++i) {
        int p = i * 4 + ti;
        db[(size_t)(p0 + p) * NC + c0 + tj] = tile[tj][p];
    }

    // bf16-hi fragment-linear + norm partials
    unsigned short* fh = g_FH[mat];
    float np = 0.f;
    #pragma unroll
    for (int it = 0; it < 2; ++it) {
        const int p  = t & 63;
        const int ko = (t >> 6) + it * 4;      // 0..7 k-octet within c-tile
        short8v hv;
        #pragma unroll
        for (int e = 0; e < 8; ++e) {
            float v = tile[ko * 8 + e][p];
            np += v * v;
            hv[e] = bf16rne(v);
        }
        const int row = p0 + p, k = c0 + ko * 8;
        size_t base = (((size_t)(b * 32 + (row >> 5)) * 8 + (k >> 4)) * 64
                       + ((k >> 3) & 1) * 32 + (row & 31)) * 8;
        *reinterpret_cast<short8v*>(fh + base) = hv;
    }
    s_np[ti][tj] = np;
    __syncthreads();
    if (t < 64)
        g_npart[mat][blockIdx.y][b * NM + p0 + t]
            = s_np[0][t] + s_np[1][t] + s_np[2][t] + s_np[3][t];
}

// ---------------------------------------------------------------------------
// 1-term bf16 MFMA distance-argmin (validated: absmax stayed 0.0). Block =
// 128m x 128n, 4 waves, monolithic 32KB B-stage via global_load_lds, A
// hi-frags in 32 VGPRs, one barrier, 32 MFMAs. XCD-chunked swizzle.
__global__ __launch_bounds__(256, 4)
void argmin7_kernel()
{
    __shared__ unsigned short lBH[4 * 8 * 512];   // 32 KB (hi only)
    __shared__ float    s_nA[128], s_nB[128];
    __shared__ float    s_cv[4][128];
    __shared__ unsigned s_ci[4][128];

    const int raw  = blockIdx.x;
    const int lblk = (raw & 7) * 128 + (raw >> 3);   // bijective XCD chunking
    const int b  = lblk >> 6;
    const int rt = (lblk >> 3) & 7;
    const int cs = lblk & 7;
    const int m0 = rt << 7;
    const int n0 = cs << 7;
    const int t  = threadIdx.x;
    const int w  = t >> 6;
    const int lane = t & 63;
    const int cl   = lane & 31;
    const int half = lane >> 5;

    // ---- stage B hi panel (4 x 32-col tiles, contiguous 32KB), linear dest
    const size_t bbase = ((size_t)(b * 32 + (n0 >> 5)) * 8) * 512;  // ushort
    #pragma unroll
    for (int i = 0; i < 8; ++i) {
        int f = i * 256 + t;                 // 0..2047 16B chunks
        __builtin_amdgcn_global_load_lds(
            (__attribute__((address_space(1))) void*)(g_FH[1] + bbase + (size_t)f * 8),
            (__attribute__((address_space(3))) void*)&lBH[f * 8], 16, 0, 0);
    }
    if (t < 128) {
        s_nA[t] = g_npart[0][0][b * NM + m0 + t] + g_npart[0][1][b * NM + m0 + t];
        s_nB[t] = g_npart[1][0][b * NM + n0 + t] + g_npart[1][1][b * NM + n0 + t];
    }

    // ---- A hi-fragments straight to registers (coalesced 1KB wave reads)
    const size_t abase = (size_t)((b * 32 + (m0 >> 5) + w) * 8) * 64 + lane;
    const short8v* FAH = (const short8v*)g_FH[0];
    short8v aH[8];
    #pragma unroll
    for (int s = 0; s < 8; ++s) aH[s] = FAH[abase + s * 64];

    float rv[16]; unsigned ri[16];
    #pragma unroll
    for (int r = 0; r < 16; ++r) { rv[r] = 3.4e38f; ri[r] = 0u; }

    __syncthreads();   // drains staging + A loads

    #pragma unroll
    for (int nt = 0; nt < 4; ++nt) {
        floatx16 acc = {};
        #pragma unroll
        for (int s = 0; s < 8; ++s) {
            short8v bh = *(const short8v*)&lBH[(nt * 8 + s) * 512 + lane * 8];
            acc = __builtin_amdgcn_mfma_f32_32x32x16_bf16(aH[s], bh, acc, 0, 0, 0);
        }
        // C/D map: col = cl (+32*nt), row(reg r) = (r&3)+8*(r>>2)+4*half (+32*w)
        {
            const float nv = s_nB[nt * 32 + cl];
            const unsigned n = (unsigned)(n0 + nt * 32 + cl);
            #pragma unroll
            for (int r = 0; r < 16; ++r) {
                float val = nv - 2.0f * acc[r];
                if (val < rv[r]) { rv[r] = val; ri[r] = n; }
            }
        }
        {
            float cv = 3.4e38f; unsigned ci = 0u;
            #pragma unroll
            for (int r = 0; r < 16; ++r) {
                int mloc = w * 32 + (r & 3) + 8 * (r >> 2) + 4 * half;
                float val = s_nA[mloc] - 2.0f * acc[r];
                if (val < cv) { cv = val; ci = (unsigned)(m0 + mloc); }
            }
            float    ov = __shfl_xor(cv, 32);
            unsigned oi = __shfl_xor(ci, 32);
            if (ov < cv || (ov == cv && oi < ci)) { cv = ov; ci = oi; }
            if (half == 0) { s_cv[w][nt * 32 + cl] = cv; s_ci[w][nt * 32 + cl] = ci; }
        }
    }

    // row-min shuffle-reduce over the 32 cols (cl), lowest-index tie-break
    #pragma unroll
    for (int off = 1; off <= 16; off <<= 1) {
        #pragma unroll
        for (int r = 0; r < 16; ++r) {
            float    ov = __shfl_xor(rv[r], off);
            unsigned oi = __shfl_xor(ri[r], off);
            if (ov < rv[r] || (ov == rv[r] && oi < ri[r])) { rv[r] = ov; ri[r] = oi; }
        }
    }
    if (cl == 0) {
        #pragma unroll
        for (int r = 0; r < 16; ++r) {
            int mloc = w * 32 + (r & 3) + 8 * (r >> 2) + 4 * half;
            g_rval[b][cs][m0 + mloc] = rv[r];
            g_ridx[b][cs][m0 + mloc] = ri[r];
        }
    }
    __syncthreads();   // s_cv complete across waves
    if (t < 128) {
        float v = s_cv[0][t]; unsigned id = s_ci[0][t];
        #pragma unroll
        for (int wv = 1; wv < 4; ++wv) {
            float ov = s_cv[wv][t]; unsigned oi = s_ci[wv][t];
            if (ov < v || (ov == v && oi < id)) { v = ov; id = oi; }
        }
        g_cval[b][rt][n0 + t] = v;
        g_cidx[b][rt][n0 + t] = id;
    }
}

// ---------------------------------------------------------------------------
// Per-position losses + fused final reduction. One block per position m.
// Mats: 0=m1, 1=nn1, 2=m2, 3=nn2. Gram on the matrix pipe (same regs as A and
// B -> Z.Z^T). Final totals via device-scope fp32 atomicAdd at the coherent
// point; ticket ordered by s_waitcnt vmcnt(0) (completion wait, NOT an L2
// writeback fence -- that was round 9's mistake). Last ticket scales + writes.
__global__ __launch_bounds__(256)
void loss_kernel(float* __restrict__ out)
{
    __shared__ float Z[4 * 16 * ZS];     // 33 KB, rows 16B-aligned
    __shared__ unsigned s_rr[2][16];
    __shared__ float red[12];
    const int m = blockIdx.x;
    const int t = threadIdx.x;

    // parallel min-combine: 256 threads = dir(2) x b(16) x split(8)
    {
        const int dir = t >> 7;
        const int b   = (t >> 3) & 15;
        const int spl = t & 7;
        float v; unsigned id;
        if (dir == 0) { v = g_rval[b][spl][m]; id = g_ridx[b][spl][m]; }
        else          { v = g_cval[b][spl][m]; id = g_cidx[b][spl][m]; }
        #pragma unroll
        for (int off = 1; off < 8; off <<= 1) {
            float    ov = __shfl_xor(v, off);
            unsigned oi = __shfl_xor(id, off);
            if (ov < v || (ov == v && oi < id)) { v = ov; id = oi; }
        }
        if (spl == 0) s_rr[dir][b] = id;
    }
    __syncthreads();

    // gather rows (thread (bb,o): 8 floats per mat) + repr from registers
    const int o  = t & 15;               // c-octet
    const int bb = t >> 4;               // batch
    const unsigned rows[4] = { (unsigned)m, s_rr[0][bb], (unsigned)m, s_rr[1][bb] };
    float4 g0[4], g1[4];
    #pragma unroll
    for (int mat = 0; mat < 4; ++mat) {
        const float* T = (mat == 0 || mat == 3) ? g_T[0] : g_T[1];
        const float* src = T + ((size_t)bb * NM + rows[mat]) * NC + o * 8;
        g0[mat] = *reinterpret_cast<const float4*>(src);
        g1[mat] = *reinterpret_cast<const float4*>(src + 4);
        *reinterpret_cast<float4*>(&Z[mat * 16 * ZS + bb * ZS + o * 8])     = g0[mat];
        *reinterpret_cast<float4*>(&Z[mat * 16 * ZS + bb * ZS + o * 8 + 4]) = g1[mat];
    }
    float racc = 0.f;
    {
        float4 d0a = make_float4(g0[0].x - g0[1].x, g0[0].y - g0[1].y,
                                 g0[0].z - g0[1].z, g0[0].w - g0[1].w);
        float4 d0b = make_float4(g1[0].x - g1[1].x, g1[0].y - g1[1].y,
                                 g1[0].z - g1[1].z, g1[0].w - g1[1].w);
        float4 d1a = make_float4(g0[2].x - g0[3].x, g0[2].y - g0[3].y,
                                 g0[2].z - g0[3].z, g0[2].w - g0[3].w);
        float4 d1b = make_float4(g1[2].x - g1[3].x, g1[2].y - g1[3].y,
                                 g1[2].z - g1[3].z, g1[2].w - g1[3].w);
        racc = d0a.x*d0a.x + d0a.y*d0a.y + d0a.z*d0a.z + d0a.w*d0a.w
             + d0b.x*d0b.x + d0b.y*d0b.y + d0b.z*d0b.z + d0b.w*d0b.w
             + d1a.x*d1a.x + d1a.y*d1a.y + d1a.z*d1a.z + d1a.w*d1a.w
             + d1b.x*d1b.x + d1b.y*d1b.y + d1b.z*d1b.z + d1b.w*d1b.w;
    }
    __syncthreads();

    // column stats, float2 tasks on ALL 256 threads: mat = t>>6, c-pair = t&63.
    // center in place, variance, std-loss, diag^2 accumulation (all fp32).
    float sacc = 0.f, qdacc = 0.f;
    {
        float* Zm = &Z[(t >> 6) * 16 * ZS + (t & 63) * 2];
        float m0 = 0.f, m1 = 0.f;
        #pragma unroll
        for (int b = 0; b < 16; ++b) {
            float2 v = *reinterpret_cast<const float2*>(&Zm[b * ZS]);
            m0 += v.x; m1 += v.y;
        }
        m0 *= 0.0625f; m1 *= 0.0625f;
        float d0 = 0.f, d1 = 0.f;
        #pragma unroll
        for (int b = 0; b < 16; ++b) {
            float2 v = *reinterpret_cast<const float2*>(&Zm[b * ZS]);
            v.x -= m0; v.y -= m1;
            *reinterpret_cast<float2*>(&Zm[b * ZS]) = v;
            d0 += v.x * v.x; d1 += v.y * v.y;
        }
        sacc = fmaxf(1.f - sqrtf(d0 * (1.f/15.f) + 1e-4f), 0.f)
             + fmaxf(1.f - sqrtf(d1 * (1.f/15.f) + 1e-4f), 0.f);
        qdacc = d0 * d0 + d1 * d1;
    }
    __syncthreads();

    // MFMA Gram: wave w -> mat w. Lane l loads Z[l&15][kc*32 + (l>>4)*8 .. +7]
    // as bf16x8; same regs fed as A and B -> acc = G rows (l>>4)*4..+3, col l&15.
    float qaacc = 0.f;
    {
        const int w    = t >> 6;
        const int lane = t & 63;
        const float* Zr = &Z[w * 16 * ZS + (lane & 15) * ZS + (lane >> 4) * 8];
        floatx4 acc = {};
        #pragma unroll
        for (int kc = 0; kc < 4; ++kc) {
            float4 v0 = *reinterpret_cast<const float4*>(Zr + kc * 32);
            float4 v1 = *reinterpret_cast<const float4*>(Zr + kc * 32 + 4);
            short8v f;
            f[0] = bf16rne(v0.x); f[1] = bf16rne(v0.y);
            f[2] = bf16rne(v0.z); f[3] = bf16rne(v0.w);
            f[4] = bf16rne(v1.x); f[5] = bf16rne(v1.y);
            f[6] = bf16rne(v1.z); f[7] = bf16rne(v1.w);
            acc = __builtin_amdgcn_mfma_f32_16x16x32_bf16(f, f, acc, 0, 0, 0);
        }
        qaacc = acc[0]*acc[0] + acc[1]*acc[1] + acc[2]*acc[2] + acc[3]*acc[3];
    }

    // block-reduce the three partials
    float v0 = racc, v1 = sacc, v2 = qaacc - qdacc;
    #pragma unroll
    for (int off = 32; off >= 1; off >>= 1) {
        v0 += __shfl_xor(v0, off);
        v1 += __shfl_xor(v1, off);
        v2 += __shfl_xor(v2, off);
    }
    const int w = t >> 6;
    if ((t & 63) == 0) { red[w] = v0; red[4 + w] = v1; red[8 + w] = v2; }
    __syncthreads();
    if (t == 0) {
        float p0 = red[0] + red[1] + red[2] + red[3];
        float p1 = red[4] + red[5] + red[6] + red[7];
        float p2 = red[8] + red[9] + red[10] + red[11];
        atomicAdd(&g_accum[0], p0);
        atomicAdd(&g_accum[1], p1);
        atomicAdd(&g_accum[2], p2);
        // completion wait: our 3 RMWs have executed at the coherent point
        // before the ticket RMW issues (cheap -- no cache writeback).
        asm volatile("s_waitcnt vmcnt(0)" ::: "memory");
        unsigned ticket = atomicAdd(&g_done, 1u);
        if (ticket == NM - 1) {
            // all 1024 blocks' adds completed at the coherent point
            float r = atomicAdd(&g_accum[0], 0.0f);
            float s = atomicAdd(&g_accum[1], 0.0f);
            float q = atomicAdd(&g_accum[2], 0.0f);
            out[0] = r * (25.0f / 4194304.0f);
            out[1] = s * (25.0f / 524288.0f);
            out[2] = q * (1.0f / (225.0f * 1024.0f * 512.0f));
            // counters re-zeroed by next call's transpose_kernel
        }
    }
}

// ---------------------------------------------------------------------------
extern "C" void kernel_launch(void* const* d_in, const int* in_sizes, int n_in,
                              void* d_out, int out_size, void* d_ws, size_t ws_size,
                              hipStream_t stream)
{
    const float* e1 = (const float*)d_in[0];
    const float* e2 = (const float*)d_in[1];
    float* out = (float*)d_out;

    transpose_kernel<<<dim3(16, 2, 32), 256, 0, stream>>>(e1, e2);
    argmin7_kernel<<<1024, 256, 0, stream>>>();
    loss_kernel<<<1024, 256, 0, stream>>>(out);
}

// Round 13
// 46.853 us; speedup vs baseline: 1.9775x; 1.9775x over previous
//
#include <hip/hip_runtime.h>
#include <hip/hip_bf16.h>
#include <math.h>

// Problem constants: B=16, C=128, M=H*W=1024.
#define NB 16
#define NC 128
#define NM 1024
#define ZS 132   // loss LDS row stride (16B-aligned, bank-shifted; 132%4==0)

typedef __attribute__((ext_vector_type(8))) short  short8v;   // 8 bf16 = 4 VGPR
typedef __attribute__((ext_vector_type(4))) float  floatx4;   // MFMA 16x16 acc
typedef __attribute__((ext_vector_type(16))) float floatx16;  // MFMA 32x32 acc

__device__ __forceinline__ short bf16rne(float v)
{
    unsigned xb = __float_as_uint(v);
    return (short)((xb + 0x7FFFu + ((xb >> 16) & 1u)) >> 16);
}

// Persistent device scratch (fully rewritten every call -> deterministic).
// g_FH: fragment-linear bf16 hi for the MFMA argmin. chunk = (b*32+row/32)*8
// + k/16 is a 1KB wave fragment; lane = ((k>>3)&1)*32 | (row&31), 8 k/lane.
// g_T: token-major fp32 (contiguous 512B rows) for the loss gather.
// NOTE (rounds 9+12): grid-scale single-point reduction inside a kernel
// (per-block __threadfence, or same-address atomicAdd from 1024 blocks)
// serializes at the coherent point on the 8-XCD part and costs 8-60us.
// The g_part[] + separate 1-block final_kernel structure is the right one.
__device__ unsigned short g_FH[2][NB * NM * NC];
__device__ float    g_T[2][NB * NM * NC];
__device__ float    g_npart[2][2][NB * NM];   // per-position norm partials (c-halves)
__device__ float    g_part[3][NM];            // per-position partials: R, S, Qraw
__device__ float    g_rval[NB][8][NM];        // row-min partials over 8 col-splits
__device__ unsigned g_ridx[NB][8][NM];
__device__ float    g_cval[NB][8][NM];        // col-min partials over 8 row-tiles
__device__ unsigned g_cidx[NB][8][NM];

// ---------------------------------------------------------------------------
// Transpose E[b][c][p] (c-major) -> g_T fp32 token-major + g_FH bf16-hi
// fragment-linear + per-position norm partials. float4 global loads (1KB/wave
// instr); LDS tile [64][65] keeps column reads conflict-free.
__global__ __launch_bounds__(256)
void transpose_kernel(const float* __restrict__ e1, const float* __restrict__ e2)
{
    __shared__ float tile[64][65];
    __shared__ float s_np[4][64];
    const int z   = blockIdx.z;
    const int b   = z >> 1;
    const int mat = z & 1;
    const float* src = mat ? e2 : e1;
    const int p0 = blockIdx.x * 64;
    const int c0 = blockIdx.y * 64;
    const int t  = threadIdx.x;
    const int tj = t & 63;
    const int ti = t >> 6;               // 0..3
    const float* sb = src + (size_t)b * NC * NM;

    // vectorized loads: task id -> (c = id>>4, q = id&15), 1KB per wave instr
    #pragma unroll
    for (int i = 0; i < 4; ++i) {
        int id = i * 256 + t;
        int c = id >> 4, q = id & 15;
        float4 v = *reinterpret_cast<const float4*>(sb + (size_t)(c0 + c) * NM + p0 + q * 4);
        tile[c][q * 4 + 0] = v.x;
        tile[c][q * 4 + 1] = v.y;
        tile[c][q * 4 + 2] = v.z;
        tile[c][q * 4 + 3] = v.w;
    }
    __syncthreads();

    // fp32 token-major rows (contiguous in c, coalesced)
    float* db = g_T[mat] + (size_t)b * NM * NC;
    #pragma unroll
    for (int i = 0; i < 16; ++i) {
        int p = i * 4 + ti;
        db[(size_t)(p0 + p) * NC + c0 + tj] = tile[tj][p];
    }

    // bf16-hi fragment-linear + norm partials
    unsigned short* fh = g_FH[mat];
    float np = 0.f;
    #pragma unroll
    for (int it = 0; it < 2; ++it) {
        const int p  = t & 63;
        const int ko = (t >> 6) + it * 4;      // 0..7 k-octet within c-tile
        short8v hv;
        #pragma unroll
        for (int e = 0; e < 8; ++e) {
            float v = tile[ko * 8 + e][p];
            np += v * v;
            hv[e] = bf16rne(v);
        }
        const int row = p0 + p, k = c0 + ko * 8;
        size_t base = (((size_t)(b * 32 + (row >> 5)) * 8 + (k >> 4)) * 64
                       + ((k >> 3) & 1) * 32 + (row & 31)) * 8;
        *reinterpret_cast<short8v*>(fh + base) = hv;
    }
    s_np[ti][tj] = np;
    __syncthreads();
    if (t < 64)
        g_npart[mat][blockIdx.y][b * NM + p0 + t]
            = s_np[0][t] + s_np[1][t] + s_np[2][t] + s_np[3][t];
}

// ---------------------------------------------------------------------------
// 1-term bf16 MFMA distance-argmin (validated: absmax stayed 0.0). Block =
// 128m x 128n, 4 waves, monolithic 32KB B-stage via global_load_lds, A
// hi-frags in 32 VGPRs, one barrier, 32 MFMAs. XCD-chunked swizzle.
__global__ __launch_bounds__(256, 4)
void argmin7_kernel()
{
    __shared__ unsigned short lBH[4 * 8 * 512];   // 32 KB (hi only)
    __shared__ float    s_nA[128], s_nB[128];
    __shared__ float    s_cv[4][128];
    __shared__ unsigned s_ci[4][128];

    const int raw  = blockIdx.x;
    const int lblk = (raw & 7) * 128 + (raw >> 3);   // bijective XCD chunking
    const int b  = lblk >> 6;
    const int rt = (lblk >> 3) & 7;
    const int cs = lblk & 7;
    const int m0 = rt << 7;
    const int n0 = cs << 7;
    const int t  = threadIdx.x;
    const int w  = t >> 6;
    const int lane = t & 63;
    const int cl   = lane & 31;
    const int half = lane >> 5;

    // ---- stage B hi panel (4 x 32-col tiles, contiguous 32KB), linear dest
    const size_t bbase = ((size_t)(b * 32 + (n0 >> 5)) * 8) * 512;  // ushort
    #pragma unroll
    for (int i = 0; i < 8; ++i) {
        int f = i * 256 + t;                 // 0..2047 16B chunks
        __builtin_amdgcn_global_load_lds(
            (__attribute__((address_space(1))) void*)(g_FH[1] + bbase + (size_t)f * 8),
            (__attribute__((address_space(3))) void*)&lBH[f * 8], 16, 0, 0);
    }
    if (t < 128) {
        s_nA[t] = g_npart[0][0][b * NM + m0 + t] + g_npart[0][1][b * NM + m0 + t];
        s_nB[t] = g_npart[1][0][b * NM + n0 + t] + g_npart[1][1][b * NM + n0 + t];
    }

    // ---- A hi-fragments straight to registers (coalesced 1KB wave reads)
    const size_t abase = (size_t)((b * 32 + (m0 >> 5) + w) * 8) * 64 + lane;
    const short8v* FAH = (const short8v*)g_FH[0];
    short8v aH[8];
    #pragma unroll
    for (int s = 0; s < 8; ++s) aH[s] = FAH[abase + s * 64];

    float rv[16]; unsigned ri[16];
    #pragma unroll
    for (int r = 0; r < 16; ++r) { rv[r] = 3.4e38f; ri[r] = 0u; }

    __syncthreads();   // drains staging + A loads

    #pragma unroll
    for (int nt = 0; nt < 4; ++nt) {
        floatx16 acc = {};
        #pragma unroll
        for (int s = 0; s < 8; ++s) {
            short8v bh = *(const short8v*)&lBH[(nt * 8 + s) * 512 + lane * 8];
            acc = __builtin_amdgcn_mfma_f32_32x32x16_bf16(aH[s], bh, acc, 0, 0, 0);
        }
        // C/D map: col = cl (+32*nt), row(reg r) = (r&3)+8*(r>>2)+4*half (+32*w)
        {
            const float nv = s_nB[nt * 32 + cl];
            const unsigned n = (unsigned)(n0 + nt * 32 + cl);
            #pragma unroll
            for (int r = 0; r < 16; ++r) {
                float val = nv - 2.0f * acc[r];
                if (val < rv[r]) { rv[r] = val; ri[r] = n; }
            }
        }
        {
            float cv = 3.4e38f; unsigned ci = 0u;
            #pragma unroll
            for (int r = 0; r < 16; ++r) {
                int mloc = w * 32 + (r & 3) + 8 * (r >> 2) + 4 * half;
                float val = s_nA[mloc] - 2.0f * acc[r];
                if (val < cv) { cv = val; ci = (unsigned)(m0 + mloc); }
            }
            float    ov = __shfl_xor(cv, 32);
            unsigned oi = __shfl_xor(ci, 32);
            if (ov < cv || (ov == cv && oi < ci)) { cv = ov; ci = oi; }
            if (half == 0) { s_cv[w][nt * 32 + cl] = cv; s_ci[w][nt * 32 + cl] = ci; }
        }
    }

    // row-min shuffle-reduce over the 32 cols (cl), lowest-index tie-break
    #pragma unroll
    for (int off = 1; off <= 16; off <<= 1) {
        #pragma unroll
        for (int r = 0; r < 16; ++r) {
            float    ov = __shfl_xor(rv[r], off);
            unsigned oi = __shfl_xor(ri[r], off);
            if (ov < rv[r] || (ov == rv[r] && oi < ri[r])) { rv[r] = ov; ri[r] = oi; }
        }
    }
    if (cl == 0) {
        #pragma unroll
        for (int r = 0; r < 16; ++r) {
            int mloc = w * 32 + (r & 3) + 8 * (r >> 2) + 4 * half;
            g_rval[b][cs][m0 + mloc] = rv[r];
            g_ridx[b][cs][m0 + mloc] = ri[r];
        }
    }
    __syncthreads();   // s_cv complete across waves
    if (t < 128) {
        float v = s_cv[0][t]; unsigned id = s_ci[0][t];
        #pragma unroll
        for (int wv = 1; wv < 4; ++wv) {
            float ov = s_cv[wv][t]; unsigned oi = s_ci[wv][t];
            if (ov < v || (ov == v && oi < id)) { v = ov; id = oi; }
        }
        g_cval[b][rt][n0 + t] = v;
        g_cidx[b][rt][n0 + t] = id;
    }
}

// ---------------------------------------------------------------------------
// Per-position losses. One block per position m. Mats: 0=m1, 1=nn1, 2=m2,
// 3=nn2. Gram computed on the matrix pipe: G = Z.Z^T via mfma_16x16x32_bf16
// with the SAME registers fed as A and B (CDNA A/B fragments share the
// (lane,slot)->k map, so D = Z.Z^T regardless of internal k order; sum of
// G^2 is also transpose-invariant). bf16 Gram error ~0.1% << 0.685 threshold.
__global__ __launch_bounds__(256)
void loss_kernel()
{
    __shared__ float Z[4 * 16 * ZS];     // 33 KB, rows 16B-aligned
    __shared__ unsigned s_rr[2][16];
    __shared__ float red[12];
    const int m = blockIdx.x;
    const int t = threadIdx.x;

    // parallel min-combine: 256 threads = dir(2) x b(16) x split(8)
    {
        const int dir = t >> 7;
        const int b   = (t >> 3) & 15;
        const int spl = t & 7;
        float v; unsigned id;
        if (dir == 0) { v = g_rval[b][spl][m]; id = g_ridx[b][spl][m]; }
        else          { v = g_cval[b][spl][m]; id = g_cidx[b][spl][m]; }
        #pragma unroll
        for (int off = 1; off < 8; off <<= 1) {
            float    ov = __shfl_xor(v, off);
            unsigned oi = __shfl_xor(id, off);
            if (ov < v || (ov == v && oi < id)) { v = ov; id = oi; }
        }
        if (spl == 0) s_rr[dir][b] = id;
    }
    __syncthreads();

    // gather rows (thread (bb,o): 8 floats per mat) + repr from registers
    const int o  = t & 15;               // c-octet
    const int bb = t >> 4;               // batch
    const unsigned rows[4] = { (unsigned)m, s_rr[0][bb], (unsigned)m, s_rr[1][bb] };
    float4 g0[4], g1[4];
    #pragma unroll
    for (int mat = 0; mat < 4; ++mat) {
        const float* T = (mat == 0 || mat == 3) ? g_T[0] : g_T[1];
        const float* src = T + ((size_t)bb * NM + rows[mat]) * NC + o * 8;
        g0[mat] = *reinterpret_cast<const float4*>(src);
        g1[mat] = *reinterpret_cast<const float4*>(src + 4);
        *reinterpret_cast<float4*>(&Z[mat * 16 * ZS + bb * ZS + o * 8])     = g0[mat];
        *reinterpret_cast<float4*>(&Z[mat * 16 * ZS + bb * ZS + o * 8 + 4]) = g1[mat];
    }
    float racc = 0.f;
    {
        float4 d0a = make_float4(g0[0].x - g0[1].x, g0[0].y - g0[1].y,
                                 g0[0].z - g0[1].z, g0[0].w - g0[1].w);
        float4 d0b = make_float4(g1[0].x - g1[1].x, g1[0].y - g1[1].y,
                                 g1[0].z - g1[1].z, g1[0].w - g1[1].w);
        float4 d1a = make_float4(g0[2].x - g0[3].x, g0[2].y - g0[3].y,
                                 g0[2].z - g0[3].z, g0[2].w - g0[3].w);
        float4 d1b = make_float4(g1[2].x - g1[3].x, g1[2].y - g1[3].y,
                                 g1[2].z - g1[3].z, g1[2].w - g1[3].w);
        racc = d0a.x*d0a.x + d0a.y*d0a.y + d0a.z*d0a.z + d0a.w*d0a.w
             + d0b.x*d0b.x + d0b.y*d0b.y + d0b.z*d0b.z + d0b.w*d0b.w
             + d1a.x*d1a.x + d1a.y*d1a.y + d1a.z*d1a.z + d1a.w*d1a.w
             + d1b.x*d1b.x + d1b.y*d1b.y + d1b.z*d1b.z + d1b.w*d1b.w;
    }
    __syncthreads();

    // column stats, float4 tasks: t<128, mat = t>>5, c-quad = t&31.
    // center in place, variance, std-loss, diag^2 accumulation (all fp32).
    float sacc = 0.f, qdacc = 0.f;
    if (t < 128) {
        float* Zm = &Z[(t >> 5) * 16 * ZS + (t & 31) * 4];
        float4 mu = make_float4(0.f, 0.f, 0.f, 0.f);
        #pragma unroll
        for (int b = 0; b < 16; ++b) {
            float4 v = *reinterpret_cast<const float4*>(&Zm[b * ZS]);
            mu.x += v.x; mu.y += v.y; mu.z += v.z; mu.w += v.w;
        }
        mu.x *= 0.0625f; mu.y *= 0.0625f; mu.z *= 0.0625f; mu.w *= 0.0625f;
        float4 d = make_float4(0.f, 0.f, 0.f, 0.f);
        #pragma unroll
        for (int b = 0; b < 16; ++b) {
            float4 v = *reinterpret_cast<const float4*>(&Zm[b * ZS]);
            v.x -= mu.x; v.y -= mu.y; v.z -= mu.z; v.w -= mu.w;
            *reinterpret_cast<float4*>(&Zm[b * ZS]) = v;
            d.x += v.x*v.x; d.y += v.y*v.y; d.z += v.z*v.z; d.w += v.w*v.w;
        }
        sacc = fmaxf(1.f - sqrtf(d.x * (1.f/15.f) + 1e-4f), 0.f)
             + fmaxf(1.f - sqrtf(d.y * (1.f/15.f) + 1e-4f), 0.f)
             + fmaxf(1.f - sqrtf(d.z * (1.f/15.f) + 1e-4f), 0.f)
             + fmaxf(1.f - sqrtf(d.w * (1.f/15.f) + 1e-4f), 0.f);
        qdacc = d.x*d.x + d.y*d.y + d.z*d.z + d.w*d.w;
    }
    __syncthreads();

    // MFMA Gram: wave w -> mat w. Lane l loads Z[l&15][kc*32 + (l>>4)*8 .. +7]
    // as bf16x8; same regs fed as A and B -> acc = G rows (l>>4)*4..+3, col l&15.
    float qaacc = 0.f;
    {
        const int w    = t >> 6;
        const int lane = t & 63;
        const float* Zr = &Z[w * 16 * ZS + (lane & 15) * ZS + (lane >> 4) * 8];
        floatx4 acc = {};
        #pragma unroll
        for (int kc = 0; kc < 4; ++kc) {
            float4 v0 = *reinterpret_cast<const float4*>(Zr + kc * 32);
            float4 v1 = *reinterpret_cast<const float4*>(Zr + kc * 32 + 4);
            short8v f;
            f[0] = bf16rne(v0.x); f[1] = bf16rne(v0.y);
            f[2] = bf16rne(v0.z); f[3] = bf16rne(v0.w);
            f[4] = bf16rne(v1.x); f[5] = bf16rne(v1.y);
            f[6] = bf16rne(v1.z); f[7] = bf16rne(v1.w);
            acc = __builtin_amdgcn_mfma_f32_16x16x32_bf16(f, f, acc, 0, 0, 0);
        }
        qaacc = acc[0]*acc[0] + acc[1]*acc[1] + acc[2]*acc[2] + acc[3]*acc[3];
    }

    // block-reduce the three partials
    float v0 = racc, v1 = sacc, v2 = qaacc - qdacc;
    #pragma unroll
    for (int off = 32; off >= 1; off >>= 1) {
        v0 += __shfl_xor(v0, off);
        v1 += __shfl_xor(v1, off);
        v2 += __shfl_xor(v2, off);
    }
    const int w = t >> 6;
    if ((t & 63) == 0) { red[w] = v0; red[4 + w] = v1; red[8 + w] = v2; }
    __syncthreads();
    if (t == 0) {
        g_part[0][m] = red[0] + red[1] + red[2] + red[3];
        g_part[1][m] = red[4] + red[5] + red[6] + red[7];
        g_part[2][m] = red[8] + red[9] + red[10] + red[11];
    }
}

// ---------------------------------------------------------------------------
__global__ __launch_bounds__(256)
void final_kernel(float* __restrict__ out)
{
    const int t = threadIdx.x;
    float r = 0.f, s = 0.f, q = 0.f;
    for (int i = t; i < NM; i += 256) {
        r += g_part[0][i];
        s += g_part[1][i];
        q += g_part[2][i];
    }
    __shared__ float red[12];
    #pragma unroll
    for (int off = 32; off >= 1; off >>= 1) {
        r += __shfl_xor(r, off);
        s += __shfl_xor(s, off);
        q += __shfl_xor(q, off);
    }
    const int w = t >> 6;
    if ((t & 63) == 0) { red[w] = r; red[4 + w] = s; red[8 + w] = q; }
    __syncthreads();
    if (t == 0) {
        r = red[0] + red[1] + red[2] + red[3];
        s = red[4] + red[5] + red[6] + red[7];
        q = red[8] + red[9] + red[10] + red[11];
        out[0] = r * (25.0f / 4194304.0f);
        out[1] = s * (25.0f / 524288.0f);
        out[2] = q * (1.0f / (225.0f * 1024.0f * 512.0f));
    }
}

// ---------------------------------------------------------------------------
extern "C" void kernel_launch(void* const* d_in, const int* in_sizes, int n_in,
                              void* d_out, int out_size, void* d_ws, size_t ws_size,
                              hipStream_t stream)
{
    const float* e1 = (const float*)d_in[0];
    const float* e2 = (const float*)d_in[1];
    float* out = (float*)d_out;

    transpose_kernel<<<dim3(16, 2, 32), 256, 0, stream>>>(e1, e2);
    argmin7_kernel<<<1024, 256, 0, stream>>>();
    loss_kernel<<<1024, 256, 0, stream>>>();
    final_kernel<<<1, 256, 0, stream>>>(out);
}

// Round 14
// 45.483 us; speedup vs baseline: 2.0371x; 1.0301x over previous
//
#include <hip/hip_runtime.h>
#include <hip/hip_bf16.h>
#include <math.h>

// Problem constants: B=16, C=128, M=H*W=1024.
#define NB 16
#define NC 128
#define NM 1024
#define ZS 132   // loss LDS row stride (16B-aligned, bank-shifted; 132%4==0)

typedef __attribute__((ext_vector_type(8))) short  short8v;   // 8 bf16 = 4 VGPR
typedef __attribute__((ext_vector_type(4))) float  floatx4;   // MFMA 16x16 acc
typedef __attribute__((ext_vector_type(16))) float floatx16;  // MFMA 32x32 acc

__device__ __forceinline__ short bf16rne(float v)
{
    unsigned xb = __float_as_uint(v);
    return (short)((xb + 0x7FFFu + ((xb >> 16) & 1u)) >> 16);
}

// Persistent device scratch (fully rewritten every call -> deterministic).
// g_FH: fragment-linear bf16 for the MFMA argmin. chunk = (b*32+row/32)*8
// + k/16 is a 1KB wave fragment; lane = ((k>>3)&1)*32 | (row&31), 8 k/lane.
// g_TH: token-major bf16 (contiguous 256B rows) for the loss gather. Loss on
// bf16-rounded embeddings: rounding noise averages out over 2M samples ->
// output bias ~1e-3 vs 0.685 threshold (measured absmax was 0.0 with fp32).
// NOTE (rounds 9+12): grid-scale single-point reduction inside a kernel
// (per-block __threadfence, or same-address atomicAdd from 1024 blocks)
// serializes at the coherent point on the 8-XCD part and costs 8-60us.
// The g_part[] + separate 1-block final_kernel structure is the right one.
__device__ unsigned short g_FH[2][NB * NM * NC];
__device__ unsigned short g_TH[2][NB * NM * NC];
__device__ float    g_npart[2][2][NB * NM];   // per-position norm partials (c-halves)
__device__ float    g_part[3][NM];            // per-position partials: R, S, Qraw
__device__ float    g_rval[NB][8][NM];        // row-min partials over 8 col-splits
__device__ unsigned g_ridx[NB][8][NM];
__device__ float    g_cval[NB][8][NM];        // col-min partials over 8 row-tiles
__device__ unsigned g_cidx[NB][8][NM];

// ---------------------------------------------------------------------------
// Transpose E[b][c][p] (c-major) -> g_TH bf16 token-major + g_FH bf16
// fragment-linear + per-position norm partials (exact fp32). float4 global
// loads (1KB/wave instr); LDS tile [64][65] keeps column reads conflict-free.
__global__ __launch_bounds__(256)
void transpose_kernel(const float* __restrict__ e1, const float* __restrict__ e2)
{
    __shared__ float tile[64][65];
    __shared__ float s_np[4][64];
    const int z   = blockIdx.z;
    const int b   = z >> 1;
    const int mat = z & 1;
    const float* src = mat ? e2 : e1;
    const int p0 = blockIdx.x * 64;
    const int c0 = blockIdx.y * 64;
    const int t  = threadIdx.x;
    const int tj = t & 63;
    const int ti = t >> 6;               // 0..3
    const float* sb = src + (size_t)b * NC * NM;

    // vectorized loads: task id -> (c = id>>4, q = id&15), 1KB per wave instr
    #pragma unroll
    for (int i = 0; i < 4; ++i) {
        int id = i * 256 + t;
        int c = id >> 4, q = id & 15;
        float4 v = *reinterpret_cast<const float4*>(sb + (size_t)(c0 + c) * NM + p0 + q * 4);
        tile[c][q * 4 + 0] = v.x;
        tile[c][q * 4 + 1] = v.y;
        tile[c][q * 4 + 2] = v.z;
        tile[c][q * 4 + 3] = v.w;
    }
    __syncthreads();

    // bf16 token-major rows (contiguous in c, coalesced ushort stores)
    unsigned short* db = g_TH[mat] + (size_t)b * NM * NC;
    #pragma unroll
    for (int i = 0; i < 16; ++i) {
        int p = i * 4 + ti;
        db[(size_t)(p0 + p) * NC + c0 + tj] = (unsigned short)bf16rne(tile[tj][p]);
    }

    // bf16 fragment-linear + norm partials (norms exact fp32)
    unsigned short* fh = g_FH[mat];
    float np = 0.f;
    #pragma unroll
    for (int it = 0; it < 2; ++it) {
        const int p  = t & 63;
        const int ko = (t >> 6) + it * 4;      // 0..7 k-octet within c-tile
        short8v hv;
        #pragma unroll
        for (int e = 0; e < 8; ++e) {
            float v = tile[ko * 8 + e][p];
            np += v * v;
            hv[e] = bf16rne(v);
        }
        const int row = p0 + p, k = c0 + ko * 8;
        size_t base = (((size_t)(b * 32 + (row >> 5)) * 8 + (k >> 4)) * 64
                       + ((k >> 3) & 1) * 32 + (row & 31)) * 8;
        *reinterpret_cast<short8v*>(fh + base) = hv;
    }
    s_np[ti][tj] = np;
    __syncthreads();
    if (t < 64)
        g_npart[mat][blockIdx.y][b * NM + p0 + t]
            = s_np[0][t] + s_np[1][t] + s_np[2][t] + s_np[3][t];
}

// ---------------------------------------------------------------------------
// 1-term bf16 MFMA distance-argmin (validated: absmax stayed 0.0). Block =
// 128m x 128n, 4 waves, monolithic 32KB B-stage via global_load_lds, A
// hi-frags in 32 VGPRs, one barrier, 32 MFMAs. XCD-chunked swizzle.
__global__ __launch_bounds__(256, 4)
void argmin7_kernel()
{
    __shared__ unsigned short lBH[4 * 8 * 512];   // 32 KB (hi only)
    __shared__ float    s_nA[128], s_nB[128];
    __shared__ float    s_cv[4][128];
    __shared__ unsigned s_ci[4][128];

    const int raw  = blockIdx.x;
    const int lblk = (raw & 7) * 128 + (raw >> 3);   // bijective XCD chunking
    const int b  = lblk >> 6;
    const int rt = (lblk >> 3) & 7;
    const int cs = lblk & 7;
    const int m0 = rt << 7;
    const int n0 = cs << 7;
    const int t  = threadIdx.x;
    const int w  = t >> 6;
    const int lane = t & 63;
    const int cl   = lane & 31;
    const int half = lane >> 5;

    // ---- stage B hi panel (4 x 32-col tiles, contiguous 32KB), linear dest
    const size_t bbase = ((size_t)(b * 32 + (n0 >> 5)) * 8) * 512;  // ushort
    #pragma unroll
    for (int i = 0; i < 8; ++i) {
        int f = i * 256 + t;                 // 0..2047 16B chunks
        __builtin_amdgcn_global_load_lds(
            (__attribute__((address_space(1))) void*)(g_FH[1] + bbase + (size_t)f * 8),
            (__attribute__((address_space(3))) void*)&lBH[f * 8], 16, 0, 0);
    }
    if (t < 128) {
        s_nA[t] = g_npart[0][0][b * NM + m0 + t] + g_npart[0][1][b * NM + m0 + t];
        s_nB[t] = g_npart[1][0][b * NM + n0 + t] + g_npart[1][1][b * NM + n0 + t];
    }

    // ---- A hi-fragments straight to registers (coalesced 1KB wave reads)
    const size_t abase = (size_t)((b * 32 + (m0 >> 5) + w) * 8) * 64 + lane;
    const short8v* FAH = (const short8v*)g_FH[0];
    short8v aH[8];
    #pragma unroll
    for (int s = 0; s < 8; ++s) aH[s] = FAH[abase + s * 64];

    float rv[16]; unsigned ri[16];
    #pragma unroll
    for (int r = 0; r < 16; ++r) { rv[r] = 3.4e38f; ri[r] = 0u; }

    __syncthreads();   // drains staging + A loads

    #pragma unroll
    for (int nt = 0; nt < 4; ++nt) {
        floatx16 acc = {};
        #pragma unroll
        for (int s = 0; s < 8; ++s) {
            short8v bh = *(const short8v*)&lBH[(nt * 8 + s) * 512 + lane * 8];
            acc = __builtin_amdgcn_mfma_f32_32x32x16_bf16(aH[s], bh, acc, 0, 0, 0);
        }
        // C/D map: col = cl (+32*nt), row(reg r) = (r&3)+8*(r>>2)+4*half (+32*w)
        {
            const float nv = s_nB[nt * 32 + cl];
            const unsigned n = (unsigned)(n0 + nt * 32 + cl);
            #pragma unroll
            for (int r = 0; r < 16; ++r) {
                float val = nv - 2.0f * acc[r];
                if (val < rv[r]) { rv[r] = val; ri[r] = n; }
            }
        }
        {
            float cv = 3.4e38f; unsigned ci = 0u;
            #pragma unroll
            for (int r = 0; r < 16; ++r) {
                int mloc = w * 32 + (r & 3) + 8 * (r >> 2) + 4 * half;
                float val = s_nA[mloc] - 2.0f * acc[r];
                if (val < cv) { cv = val; ci = (unsigned)(m0 + mloc); }
            }
            float    ov = __shfl_xor(cv, 32);
            unsigned oi = __shfl_xor(ci, 32);
            if (ov < cv || (ov == cv && oi < ci)) { cv = ov; ci = oi; }
            if (half == 0) { s_cv[w][nt * 32 + cl] = cv; s_ci[w][nt * 32 + cl] = ci; }
        }
    }

    // row-min shuffle-reduce over the 32 cols (cl), lowest-index tie-break
    #pragma unroll
    for (int off = 1; off <= 16; off <<= 1) {
        #pragma unroll
        for (int r = 0; r < 16; ++r) {
            float    ov = __shfl_xor(rv[r], off);
            unsigned oi = __shfl_xor(ri[r], off);
            if (ov < rv[r] || (ov == rv[r] && oi < ri[r])) { rv[r] = ov; ri[r] = oi; }
        }
    }
    if (cl == 0) {
        #pragma unroll
        for (int r = 0; r < 16; ++r) {
            int mloc = w * 32 + (r & 3) + 8 * (r >> 2) + 4 * half;
            g_rval[b][cs][m0 + mloc] = rv[r];
            g_ridx[b][cs][m0 + mloc] = ri[r];
        }
    }
    __syncthreads();   // s_cv complete across waves
    if (t < 128) {
        float v = s_cv[0][t]; unsigned id = s_ci[0][t];
        #pragma unroll
        for (int wv = 1; wv < 4; ++wv) {
            float ov = s_cv[wv][t]; unsigned oi = s_ci[wv][t];
            if (ov < v || (ov == v && oi < id)) { v = ov; id = oi; }
        }
        g_cval[b][rt][n0 + t] = v;
        g_cidx[b][rt][n0 + t] = id;
    }
}

// ---------------------------------------------------------------------------
// Per-position losses. One block per position m. Mats: 0=m1, 1=nn1, 2=m2,
// 3=nn2; rows gathered as bf16 (256B contiguous) and widened to fp32. Gram on
// the matrix pipe: same regs fed as A and B -> Z.Z^T (A/B fragments share the
// (lane,slot)->k map; sum of G^2 is transpose-invariant). Since Z holds bf16-
// exact values, the Gram's bf16 re-round is exact up to fp32 centering.
__global__ __launch_bounds__(256)
void loss_kernel()
{
    __shared__ float Z[4 * 16 * ZS];     // 33 KB, rows 16B-aligned
    __shared__ unsigned s_rr[2][16];
    __shared__ float red[12];
    const int m = blockIdx.x;
    const int t = threadIdx.x;

    // parallel min-combine: 256 threads = dir(2) x b(16) x split(8)
    {
        const int dir = t >> 7;
        const int b   = (t >> 3) & 15;
        const int spl = t & 7;
        float v; unsigned id;
        if (dir == 0) { v = g_rval[b][spl][m]; id = g_ridx[b][spl][m]; }
        else          { v = g_cval[b][spl][m]; id = g_cidx[b][spl][m]; }
        #pragma unroll
        for (int off = 1; off < 8; off <<= 1) {
            float    ov = __shfl_xor(v, off);
            unsigned oi = __shfl_xor(id, off);
            if (ov < v || (ov == v && oi < id)) { v = ov; id = oi; }
        }
        if (spl == 0) s_rr[dir][b] = id;
    }
    __syncthreads();

    // gather rows (thread (bb,o): 8 bf16 per mat), widen, repr from registers
    const int o  = t & 15;               // c-octet
    const int bb = t >> 4;               // batch
    const unsigned rows[4] = { (unsigned)m, s_rr[0][bb], (unsigned)m, s_rr[1][bb] };
    float z[4][8];
    #pragma unroll
    for (int mat = 0; mat < 4; ++mat) {
        const unsigned short* TH = (mat == 0 || mat == 3) ? g_TH[0] : g_TH[1];
        const unsigned short* src = TH + ((size_t)bb * NM + rows[mat]) * NC + o * 8;
        short8v hv = *reinterpret_cast<const short8v*>(src);
        #pragma unroll
        for (int e = 0; e < 8; ++e)
            z[mat][e] = __uint_as_float(((unsigned)(unsigned short)hv[e]) << 16);
        #pragma unroll
        for (int e = 0; e < 8; e += 4) {
            float4 v = make_float4(z[mat][e], z[mat][e+1], z[mat][e+2], z[mat][e+3]);
            *reinterpret_cast<float4*>(&Z[mat * 16 * ZS + bb * ZS + o * 8 + e]) = v;
        }
    }
    float racc = 0.f;
    #pragma unroll
    for (int e = 0; e < 8; ++e) {
        float d0 = z[0][e] - z[1][e];
        float d1 = z[2][e] - z[3][e];
        racc += d0 * d0 + d1 * d1;
    }
    __syncthreads();

    // column stats, float4 tasks: t<128, mat = t>>5, c-quad = t&31.
    // center in place, variance, std-loss, diag^2 accumulation (all fp32).
    float sacc = 0.f, qdacc = 0.f;
    if (t < 128) {
        float* Zm = &Z[(t >> 5) * 16 * ZS + (t & 31) * 4];
        float4 mu = make_float4(0.f, 0.f, 0.f, 0.f);
        #pragma unroll
        for (int b = 0; b < 16; ++b) {
            float4 v = *reinterpret_cast<const float4*>(&Zm[b * ZS]);
            mu.x += v.x; mu.y += v.y; mu.z += v.z; mu.w += v.w;
        }
        mu.x *= 0.0625f; mu.y *= 0.0625f; mu.z *= 0.0625f; mu.w *= 0.0625f;
        float4 d = make_float4(0.f, 0.f, 0.f, 0.f);
        #pragma unroll
        for (int b = 0; b < 16; ++b) {
            float4 v = *reinterpret_cast<const float4*>(&Zm[b * ZS]);
            v.x -= mu.x; v.y -= mu.y; v.z -= mu.z; v.w -= mu.w;
            *reinterpret_cast<float4*>(&Zm[b * ZS]) = v;
            d.x += v.x*v.x; d.y += v.y*v.y; d.z += v.z*v.z; d.w += v.w*v.w;
        }
        sacc = fmaxf(1.f - sqrtf(d.x * (1.f/15.f) + 1e-4f), 0.f)
             + fmaxf(1.f - sqrtf(d.y * (1.f/15.f) + 1e-4f), 0.f)
             + fmaxf(1.f - sqrtf(d.z * (1.f/15.f) + 1e-4f), 0.f)
             + fmaxf(1.f - sqrtf(d.w * (1.f/15.f) + 1e-4f), 0.f);
        qdacc = d.x*d.x + d.y*d.y + d.z*d.z + d.w*d.w;
    }
    __syncthreads();

    // MFMA Gram: wave w -> mat w. Lane l loads Z[l&15][kc*32 + (l>>4)*8 .. +7]
    // as bf16x8; same regs fed as A and B -> acc = G rows (l>>4)*4..+3, col l&15.
    float qaacc = 0.f;
    {
        const int w    = t >> 6;
        const int lane = t & 63;
        const float* Zr = &Z[w * 16 * ZS + (lane & 15) * ZS + (lane >> 4) * 8];
        floatx4 acc = {};
        #pragma unroll
        for (int kc = 0; kc < 4; ++kc) {
            float4 v0 = *reinterpret_cast<const float4*>(Zr + kc * 32);
            float4 v1 = *reinterpret_cast<const float4*>(Zr + kc * 32 + 4);
            short8v f;
            f[0] = bf16rne(v0.x); f[1] = bf16rne(v0.y);
            f[2] = bf16rne(v0.z); f[3] = bf16rne(v0.w);
            f[4] = bf16rne(v1.x); f[5] = bf16rne(v1.y);
            f[6] = bf16rne(v1.z); f[7] = bf16rne(v1.w);
            acc = __builtin_amdgcn_mfma_f32_16x16x32_bf16(f, f, acc, 0, 0, 0);
        }
        qaacc = acc[0]*acc[0] + acc[1]*acc[1] + acc[2]*acc[2] + acc[3]*acc[3];
    }

    // block-reduce the three partials
    float v0 = racc, v1 = sacc, v2 = qaacc - qdacc;
    #pragma unroll
    for (int off = 32; off >= 1; off >>= 1) {
        v0 += __shfl_xor(v0, off);
        v1 += __shfl_xor(v1, off);
        v2 += __shfl_xor(v2, off);
    }
    const int w = t >> 6;
    if ((t & 63) == 0) { red[w] = v0; red[4 + w] = v1; red[8 + w] = v2; }
    __syncthreads();
    if (t == 0) {
        g_part[0][m] = red[0] + red[1] + red[2] + red[3];
        g_part[1][m] = red[4] + red[5] + red[6] + red[7];
        g_part[2][m] = red[8] + red[9] + red[10] + red[11];
    }
}

// ---------------------------------------------------------------------------
__global__ __launch_bounds__(256)
void final_kernel(float* __restrict__ out)
{
    const int t = threadIdx.x;
    float r = 0.f, s = 0.f, q = 0.f;
    for (int i = t; i < NM; i += 256) {
        r += g_part[0][i];
        s += g_part[1][i];
        q += g_part[2][i];
    }
    __shared__ float red[12];
    #pragma unroll
    for (int off = 32; off >= 1; off >>= 1) {
        r += __shfl_xor(r, off);
        s += __shfl_xor(s, off);
        q += __shfl_xor(q, off);
    }
    const int w = t >> 6;
    if ((t & 63) == 0) { red[w] = r; red[4 + w] = s; red[8 + w] = q; }
    __syncthreads();
    if (t == 0) {
        r = red[0] + red[1] + red[2] + red[3];
        s = red[4] + red[5] + red[6] + red[7];
        q = red[8] + red[9] + red[10] + red[11];
        out[0] = r * (25.0f / 4194304.0f);
        out[1] = s * (25.0f / 524288.0f);
        out[2] = q * (1.0f / (225.0f * 1024.0f * 512.0f));
    }
}

// ---------------------------------------------------------------------------
extern "C" void kernel_launch(void* const* d_in, const int* in_sizes, int n_in,
                              void* d_out, int out_size, void* d_ws, size_t ws_size,
                              hipStream_t stream)
{
    const float* e1 = (const float*)d_in[0];
    const float* e2 = (const float*)d_in[1];
    float* out = (float*)d_out;

    transpose_kernel<<<dim3(16, 2, 32), 256, 0, stream>>>(e1, e2);
    argmin7_kernel<<<1024, 256, 0, stream>>>();
    loss_kernel<<<1024, 256, 0, stream>>>();
    final_kernel<<<1, 256, 0, stream>>>(out);
}